// Round 1
// baseline (478.438 us; speedup 1.0000x reference)
//
#include <hip/hip_runtime.h>
#include <math.h>

#define B_ 32
#define N_ 512
#define F_ 1024
#define EPS 1e-6f

// ---------------------------------------------------------------------------
// Kernel A: per-row sum and sum-of-squares. One wave (64 lanes) per row.
// ---------------------------------------------------------------------------
__global__ __launch_bounds__(256) void rowsum_kernel(const float* __restrict__ x,
                                                     float* __restrict__ sq,
                                                     float* __restrict__ s) {
    int row  = blockIdx.x * 4 + (threadIdx.x >> 6);   // B_*N_ rows total
    int lane = threadIdx.x & 63;
    const float4* xr = (const float4*)(x + (size_t)row * F_);  // 256 float4 per row
    float a1 = 0.f, a2 = 0.f;
#pragma unroll
    for (int it = 0; it < 4; ++it) {
        float4 v = xr[lane + it * 64];
        a1 += v.x + v.y + v.z + v.w;
        a2 += v.x * v.x + v.y * v.y + v.z * v.z + v.w * v.w;
    }
#pragma unroll
    for (int off = 32; off > 0; off >>= 1) {
        a1 += __shfl_xor(a1, off);
        a2 += __shfl_xor(a2, off);
    }
    if (lane == 0) {
        s[row]  = a1;
        sq[row] = a2;
    }
}

// ---------------------------------------------------------------------------
// Kernel B: dist[b,i,j] = ||x_i - x_j + eps||, with exact-zero diagonal.
// 64x64 output tile per block, BK=16, 256 threads, 4x4 acc per thread.
// ---------------------------------------------------------------------------
__global__ __launch_bounds__(256) void dist_kernel(const float* __restrict__ x,
                                                   const float* __restrict__ sq,
                                                   const float* __restrict__ s,
                                                   float* __restrict__ dist) {
    const int b   = blockIdx.z;
    const int ib0 = blockIdx.y * 64;
    const int jb0 = blockIdx.x * 64;
    __shared__ float As[16][68];   // [k][i], pad 68 -> 16B-aligned rows, <=2-way bank alias
    __shared__ float Bs[16][68];   // [k][j]

    const float* Xb = x + (size_t)b * N_ * F_;
    const int tid   = threadIdx.x;
    const int lrow  = tid >> 2;           // 0..63
    const int lcol4 = (tid & 3) * 4;      // 0,4,8,12
    const int tx4   = (tid & 15) * 4;     // j sub-tile
    const int ty4   = (tid >> 4) * 4;     // i sub-tile

    float acc[4][4] = {};

    for (int k0 = 0; k0 < F_; k0 += 16) {
        float4 av = *(const float4*)(Xb + (size_t)(ib0 + lrow) * F_ + k0 + lcol4);
        float4 bv = *(const float4*)(Xb + (size_t)(jb0 + lrow) * F_ + k0 + lcol4);
        __syncthreads();
        As[lcol4 + 0][lrow] = av.x; As[lcol4 + 1][lrow] = av.y;
        As[lcol4 + 2][lrow] = av.z; As[lcol4 + 3][lrow] = av.w;
        Bs[lcol4 + 0][lrow] = bv.x; Bs[lcol4 + 1][lrow] = bv.y;
        Bs[lcol4 + 2][lrow] = bv.z; Bs[lcol4 + 3][lrow] = bv.w;
        __syncthreads();
#pragma unroll
        for (int k = 0; k < 16; ++k) {
            float ar[4], br[4];
#pragma unroll
            for (int t = 0; t < 4; ++t) { ar[t] = As[k][ty4 + t]; br[t] = Bs[k][tx4 + t]; }
#pragma unroll
            for (int mi = 0; mi < 4; ++mi)
#pragma unroll
                for (int ni = 0; ni < 4; ++ni)
                    acc[mi][ni] = fmaf(ar[mi], br[ni], acc[mi][ni]);
        }
    }

    // epilogue: d2 = sq_i + sq_j - 2*dot + 2*eps*(s_i - s_j) + F*eps^2
    float sqi[4], si[4], sqj[4], sj[4];
#pragma unroll
    for (int t = 0; t < 4; ++t) {
        sqi[t] = sq[b * N_ + ib0 + ty4 + t];
        si[t]  = s [b * N_ + ib0 + ty4 + t];
        sqj[t] = sq[b * N_ + jb0 + tx4 + t];
        sj[t]  = s [b * N_ + jb0 + tx4 + t];
    }
#pragma unroll
    for (int mi = 0; mi < 4; ++mi) {
        int gi = ib0 + ty4 + mi;
        float4 o;
        float v[4];
#pragma unroll
        for (int ni = 0; ni < 4; ++ni) {
            int gj = jb0 + tx4 + ni;
            float d2 = sqi[mi] + sqj[ni] - 2.f * acc[mi][ni]
                     + 2.f * EPS * (si[mi] - sj[ni]) + (float)F_ * EPS * EPS;
            float d = sqrtf(fmaxf(d2, 0.f));
            v[ni] = (gi == gj) ? 0.f : d;
        }
        o.x = v[0]; o.y = v[1]; o.z = v[2]; o.w = v[3];
        *(float4*)(dist + ((size_t)(b * N_ + gi)) * N_ + jb0 + tx4) = o;
    }
}

// ---------------------------------------------------------------------------
// Kernel C1: partial column softmax stats (max + sum-exp) over i-chunks of 64.
// grid: (N/256, 8, B), 256 threads; thread owns one column j.
// ---------------------------------------------------------------------------
__global__ __launch_bounds__(256) void softmax_p1(const float* __restrict__ dist,
                                                  float* __restrict__ pm,
                                                  float* __restrict__ pl) {
    int b = blockIdx.z, ic = blockIdx.y;
    int j = blockIdx.x * 256 + threadIdx.x;
    const float* dcol = dist + ((size_t)(b * N_) + ic * 64) * N_ + j;
    float mx = -1e30f, sum = 0.f;
    for (int ii = 0; ii < 64; ++ii) {
        float v = dcol[(size_t)ii * N_];
        if (v > mx) { sum = sum * __expf(mx - v) + 1.f; mx = v; }
        else        { sum += __expf(v - mx); }
    }
    pm[((size_t)ic * B_ + b) * N_ + j] = mx;
    pl[((size_t)ic * B_ + b) * N_ + j] = sum;
}

// Kernel C2: combine the 8 partials -> column max m and reciprocal denom rl.
__global__ __launch_bounds__(256) void softmax_p2(const float* __restrict__ pm,
                                                  const float* __restrict__ pl,
                                                  float* __restrict__ m,
                                                  float* __restrict__ rl) {
    int b = blockIdx.y;
    int j = blockIdx.x * 256 + threadIdx.x;
    float mx = -1e30f;
#pragma unroll
    for (int c = 0; c < 8; ++c) mx = fmaxf(mx, pm[((size_t)c * B_ + b) * N_ + j]);
    float l = 0.f;
#pragma unroll
    for (int c = 0; c < 8; ++c)
        l += pl[((size_t)c * B_ + b) * N_ + j] * __expf(pm[((size_t)c * B_ + b) * N_ + j] - mx);
    m[b * N_ + j]  = mx;
    rl[b * N_ + j] = 1.f / l;
}

// ---------------------------------------------------------------------------
// Kernel D: out[b,i,k] = sum_j softmax(dist)[b,i,j] * W[k,j]
// P computed on the fly: p = exp(dist - m_j) * rl_j. Same 64x64 tiling.
// ---------------------------------------------------------------------------
__global__ __launch_bounds__(256) void out_kernel(const float* __restrict__ dist,
                                                  const float* __restrict__ m,
                                                  const float* __restrict__ rl,
                                                  const float* __restrict__ W,
                                                  float* __restrict__ out) {
    const int b  = blockIdx.z;
    const int i0 = blockIdx.y * 64;
    const int k0 = blockIdx.x * 64;
    __shared__ float Ps[16][68];   // [j][i]
    __shared__ float Ws[16][68];   // [j][k]

    const int tid   = threadIdx.x;
    const int lrow  = tid >> 2;
    const int lcol4 = (tid & 3) * 4;
    const int tx4   = (tid & 15) * 4;   // k sub-tile
    const int ty4   = (tid >> 4) * 4;   // i sub-tile

    float acc[4][4] = {};

    for (int j0 = 0; j0 < N_; j0 += 16) {
        float4 dv  = *(const float4*)(dist + ((size_t)(b * N_ + i0 + lrow)) * N_ + j0 + lcol4);
        float4 mj  = *(const float4*)(m  + b * N_ + j0 + lcol4);
        float4 rj  = *(const float4*)(rl + b * N_ + j0 + lcol4);
        float4 wv  = *(const float4*)(W + (size_t)(k0 + lrow) * N_ + j0 + lcol4);
        __syncthreads();
        Ps[lcol4 + 0][lrow] = __expf(dv.x - mj.x) * rj.x;
        Ps[lcol4 + 1][lrow] = __expf(dv.y - mj.y) * rj.y;
        Ps[lcol4 + 2][lrow] = __expf(dv.z - mj.z) * rj.z;
        Ps[lcol4 + 3][lrow] = __expf(dv.w - mj.w) * rj.w;
        Ws[lcol4 + 0][lrow] = wv.x; Ws[lcol4 + 1][lrow] = wv.y;
        Ws[lcol4 + 2][lrow] = wv.z; Ws[lcol4 + 3][lrow] = wv.w;
        __syncthreads();
#pragma unroll
        for (int k = 0; k < 16; ++k) {
            float pr[4], wr[4];
#pragma unroll
            for (int t = 0; t < 4; ++t) { pr[t] = Ps[k][ty4 + t]; wr[t] = Ws[k][tx4 + t]; }
#pragma unroll
            for (int mi = 0; mi < 4; ++mi)
#pragma unroll
                for (int ni = 0; ni < 4; ++ni)
                    acc[mi][ni] = fmaf(pr[mi], wr[ni], acc[mi][ni]);
        }
    }

#pragma unroll
    for (int mi = 0; mi < 4; ++mi) {
        float4 o;
        o.x = acc[mi][0]; o.y = acc[mi][1]; o.z = acc[mi][2]; o.w = acc[mi][3];
        *(float4*)(out + ((size_t)(b * N_ + i0 + ty4 + mi)) * N_ + k0 + tx4) = o;
    }
}

// ---------------------------------------------------------------------------
extern "C" void kernel_launch(void* const* d_in, const int* in_sizes, int n_in,
                              void* d_out, int out_size, void* d_ws, size_t ws_size,
                              hipStream_t stream) {
    const float* x = (const float*)d_in[0];
    const float* W = (const float*)d_in[1];
    float* out = (float*)d_out;

    float* ws   = (float*)d_ws;
    float* dist = ws;                                   // B*N*N
    float* sq   = dist + (size_t)B_ * N_ * N_;          // B*N
    float* s    = sq + B_ * N_;                         // B*N
    float* m    = s  + B_ * N_;                         // B*N
    float* rl   = m  + B_ * N_;                         // B*N
    float* pm   = rl + B_ * N_;                         // 8*B*N
    float* pl   = pm + 8 * B_ * N_;                     // 8*B*N

    rowsum_kernel<<<B_ * N_ / 4, 256, 0, stream>>>(x, sq, s);
    dist_kernel<<<dim3(N_ / 64, N_ / 64, B_), 256, 0, stream>>>(x, sq, s, dist);
    softmax_p1<<<dim3(N_ / 256, 8, B_), 256, 0, stream>>>(dist, pm, pl);
    softmax_p2<<<dim3(N_ / 256, B_), 256, 0, stream>>>(pm, pl, m, rl);
    out_kernel<<<dim3(N_ / 64, N_ / 64, B_), 256, 0, stream>>>(dist, m, rl, W, out);
}

// Round 2
// 240.123 us; speedup vs baseline: 1.9925x; 1.9925x over previous
//
#include <hip/hip_runtime.h>
#include <math.h>

#define B_ 32
#define N_ 512
#define F_ 1024
#define EPS 1e-6f

typedef __bf16 bf8v __attribute__((ext_vector_type(8)));
typedef __bf16 bf4v __attribute__((ext_vector_type(4)));
typedef float  f4v  __attribute__((ext_vector_type(4)));

__device__ __forceinline__ void gl_lds16(const void* g, void* l) {
    __builtin_amdgcn_global_load_lds(
        (const __attribute__((address_space(1))) unsigned int*)g,
        (__attribute__((address_space(3))) unsigned int*)l, 16, 0, 0);
}

// ---------------------------------------------------------------------------
// Kernel A: per-row sum/sumsq + split-bf16 conversion x -> xhi + xlo.
// One wave per row (F=1024 -> 4 float4 per lane).
// ---------------------------------------------------------------------------
__global__ __launch_bounds__(256) void rowsumcvt_kernel(const float* __restrict__ x,
                                                        float* __restrict__ sq,
                                                        float* __restrict__ s,
                                                        __bf16* __restrict__ xhi,
                                                        __bf16* __restrict__ xlo) {
    int row  = blockIdx.x * 4 + (threadIdx.x >> 6);
    int lane = threadIdx.x & 63;
    const float4* xr = (const float4*)(x + (size_t)row * F_);
    float a1 = 0.f, a2 = 0.f;
#pragma unroll
    for (int it = 0; it < 4; ++it) {
        float4 v = xr[lane + it * 64];
        a1 += v.x + v.y + v.z + v.w;
        a2 += v.x * v.x + v.y * v.y + v.z * v.z + v.w * v.w;
        bf4v h, l;
        h[0] = (__bf16)v.x; h[1] = (__bf16)v.y; h[2] = (__bf16)v.z; h[3] = (__bf16)v.w;
        l[0] = (__bf16)(v.x - (float)h[0]);
        l[1] = (__bf16)(v.y - (float)h[1]);
        l[2] = (__bf16)(v.z - (float)h[2]);
        l[3] = (__bf16)(v.w - (float)h[3]);
        size_t e = (size_t)row * F_ + (size_t)(lane + it * 64) * 4;
        *(bf4v*)&xhi[e] = h;
        *(bf4v*)&xlo[e] = l;
    }
#pragma unroll
    for (int off = 32; off > 0; off >>= 1) {
        a1 += __shfl_xor(a1, off);
        a2 += __shfl_xor(a2, off);
    }
    if (lane == 0) { s[row] = a1; sq[row] = a2; }
}

// W -> bf16
__global__ __launch_bounds__(256) void wcvt_kernel(const float* __restrict__ W,
                                                   __bf16* __restrict__ Wb) {
    size_t e = ((size_t)blockIdx.x * 256 + threadIdx.x) * 4;
    float4 v = *(const float4*)(W + e);
    bf4v h;
    h[0] = (__bf16)v.x; h[1] = (__bf16)v.y; h[2] = (__bf16)v.z; h[3] = (__bf16)v.w;
    *(bf4v*)&Wb[e] = h;
}

// ---------------------------------------------------------------------------
// Kernel B: dist via split-bf16 MFMA GEMM. 128x128 tile, BK=32, 256 threads,
// wave computes 64x64 (4x4 frags of 16x16x32). dot = hh + hl + lh.
// ---------------------------------------------------------------------------
__global__ __launch_bounds__(256) void dist_mfma(const __bf16* __restrict__ xhi,
                                                 const __bf16* __restrict__ xlo,
                                                 const float* __restrict__ sq,
                                                 const float* __restrict__ s,
                                                 float* __restrict__ dist) {
    const int b  = blockIdx.z;
    const int i0 = blockIdx.y * 128;
    const int j0 = blockIdx.x * 128;

    __shared__ __align__(16) __bf16 Ah[128 * 32];
    __shared__ __align__(16) __bf16 Al[128 * 32];
    __shared__ __align__(16) __bf16 Bh[128 * 32];
    __shared__ __align__(16) __bf16 Bl[128 * 32];

    const int tid  = threadIdx.x;
    const int lane = tid & 63;
    const int w    = tid >> 6;
    const int im   = (w >> 1) * 64;
    const int jn   = (w & 1) * 64;
    const int fr   = lane & 15;
    const int fk   = (lane >> 4) * 8;
    const int q4   = (lane >> 4) * 4;

    // staging source: thread covers row tid/4 (+64 per t), k-chunk (tid%4)*8
    const int srow = tid >> 2;
    const int scol = (tid & 3) * 8;
    const size_t aBase = ((size_t)(b * N_ + i0 + srow)) * F_ + scol;
    const size_t bBase = ((size_t)(b * N_ + j0 + srow)) * F_ + scol;

    f4v acc[4][4] = {};

    for (int k0 = 0; k0 < F_; k0 += 32) {
#pragma unroll
        for (int t = 0; t < 2; ++t) {
            size_t so = (size_t)t * 64 * F_ + k0;
            int    dd = t * 2048 + tid * 8;
            gl_lds16(xhi + aBase + so, &Ah[dd]);
            gl_lds16(xlo + aBase + so, &Al[dd]);
            gl_lds16(xhi + bBase + so, &Bh[dd]);
            gl_lds16(xlo + bBase + so, &Bl[dd]);
        }
        __syncthreads();   // drains vmcnt -> LDS filled

        bf8v ah[4], al[4], bh[4], bl[4];
#pragma unroll
        for (int mi = 0; mi < 4; ++mi) {
            int ro = (im + mi * 16 + fr) * 32 + fk;
            ah[mi] = *(const bf8v*)&Ah[ro];
            al[mi] = *(const bf8v*)&Al[ro];
        }
#pragma unroll
        for (int ni = 0; ni < 4; ++ni) {
            int ro = (jn + ni * 16 + fr) * 32 + fk;
            bh[ni] = *(const bf8v*)&Bh[ro];
            bl[ni] = *(const bf8v*)&Bl[ro];
        }
#pragma unroll
        for (int mi = 0; mi < 4; ++mi)
#pragma unroll
            for (int ni = 0; ni < 4; ++ni)
                acc[mi][ni] = __builtin_amdgcn_mfma_f32_16x16x32_bf16(ah[mi], bh[ni], acc[mi][ni], 0, 0, 0);
#pragma unroll
        for (int mi = 0; mi < 4; ++mi)
#pragma unroll
            for (int ni = 0; ni < 4; ++ni)
                acc[mi][ni] = __builtin_amdgcn_mfma_f32_16x16x32_bf16(ah[mi], bl[ni], acc[mi][ni], 0, 0, 0);
#pragma unroll
        for (int mi = 0; mi < 4; ++mi)
#pragma unroll
            for (int ni = 0; ni < 4; ++ni)
                acc[mi][ni] = __builtin_amdgcn_mfma_f32_16x16x32_bf16(al[mi], bh[ni], acc[mi][ni], 0, 0, 0);

        __syncthreads();   // all reads done before next stage overwrites
    }

    // epilogue
    float sqj[4], sj[4];
#pragma unroll
    for (int ni = 0; ni < 4; ++ni) {
        int j = j0 + jn + ni * 16 + fr;
        sqj[ni] = sq[b * N_ + j];
        sj[ni]  = s [b * N_ + j];
    }
#pragma unroll
    for (int mi = 0; mi < 4; ++mi)
#pragma unroll
        for (int r = 0; r < 4; ++r) {
            int i = i0 + im + mi * 16 + q4 + r;
            float sqi = sq[b * N_ + i];
            float si  = s [b * N_ + i];
#pragma unroll
            for (int ni = 0; ni < 4; ++ni) {
                int j = j0 + jn + ni * 16 + fr;
                float d2 = sqi + sqj[ni] - 2.f * acc[mi][ni][r]
                         + 2.f * EPS * (si - sj[ni]) + (float)F_ * EPS * EPS;
                float dd = (i == j) ? 0.f : sqrtf(fmaxf(d2, 0.f));
                dist[((size_t)(b * N_ + i)) * N_ + j] = dd;
            }
        }
}

// ---------------------------------------------------------------------------
// Kernel C1: partial column softmax stats over i-chunks of 64.
// ---------------------------------------------------------------------------
__global__ __launch_bounds__(256) void softmax_p1(const float* __restrict__ dist,
                                                  float* __restrict__ pm,
                                                  float* __restrict__ pl) {
    int b = blockIdx.z, ic = blockIdx.y;
    int j = blockIdx.x * 256 + threadIdx.x;
    const float* dcol = dist + ((size_t)(b * N_) + ic * 64) * N_ + j;
    float mx = -1e30f, sum = 0.f;
    for (int ii = 0; ii < 64; ++ii) {
        float v = dcol[(size_t)ii * N_];
        if (v > mx) { sum = sum * __expf(mx - v) + 1.f; mx = v; }
        else        { sum += __expf(v - mx); }
    }
    pm[((size_t)ic * B_ + b) * N_ + j] = mx;
    pl[((size_t)ic * B_ + b) * N_ + j] = sum;
}

// ---------------------------------------------------------------------------
// Kernel C2+P: combine partials (per block, redundant, cheap) and emit
// P = softmax(dist) in bf16. Block = (i-chunk of 128 rows) x batch.
// ---------------------------------------------------------------------------
__global__ __launch_bounds__(256) void pcvt_kernel(const float* __restrict__ dist,
                                                   const float* __restrict__ pm,
                                                   const float* __restrict__ pl,
                                                   __bf16* __restrict__ P) {
    __shared__ float ms[N_], rls[N_];
    const int b = blockIdx.y, ic = blockIdx.x;
    const int tid = threadIdx.x;

    for (int j = tid; j < N_; j += 256) {
        float mx = -1e30f;
#pragma unroll
        for (int c = 0; c < 8; ++c) mx = fmaxf(mx, pm[((size_t)c * B_ + b) * N_ + j]);
        float l = 0.f;
#pragma unroll
        for (int c = 0; c < 8; ++c)
            l += pl[((size_t)c * B_ + b) * N_ + j] * __expf(pm[((size_t)c * B_ + b) * N_ + j] - mx);
        ms[j]  = mx;
        rls[j] = 1.f / l;
    }
    __syncthreads();

    const size_t base = ((size_t)(b * N_) + ic * 128) * N_;
    for (int it = 0; it < 64; ++it) {
        int flat = it * 1024 + tid * 4;
        float4 d = *(const float4*)(dist + base + flat);
        int col = flat & (N_ - 1);
        bf4v p;
        p[0] = (__bf16)(__expf(d.x - ms[col + 0]) * rls[col + 0]);
        p[1] = (__bf16)(__expf(d.y - ms[col + 1]) * rls[col + 1]);
        p[2] = (__bf16)(__expf(d.z - ms[col + 2]) * rls[col + 2]);
        p[3] = (__bf16)(__expf(d.w - ms[col + 3]) * rls[col + 3]);
        *(bf4v*)&P[base + flat] = p;
    }
}

// ---------------------------------------------------------------------------
// Kernel D: out = P @ W^T via bf16 MFMA. Same 128x128 / BK=32 structure.
// ---------------------------------------------------------------------------
__global__ __launch_bounds__(256) void out_mfma(const __bf16* __restrict__ P,
                                                const __bf16* __restrict__ Wb,
                                                float* __restrict__ out) {
    const int b   = blockIdx.z;
    const int i0  = blockIdx.y * 128;
    const int k0o = blockIdx.x * 128;

    __shared__ __align__(16) __bf16 As[128 * 32];
    __shared__ __align__(16) __bf16 Bs[128 * 32];

    const int tid  = threadIdx.x;
    const int lane = tid & 63;
    const int w    = tid >> 6;
    const int im   = (w >> 1) * 64;
    const int jn   = (w & 1) * 64;
    const int fr   = lane & 15;
    const int fk   = (lane >> 4) * 8;
    const int q4   = (lane >> 4) * 4;

    const int srow = tid >> 2;
    const int scol = (tid & 3) * 8;
    const size_t aBase = ((size_t)(b * N_ + i0 + srow)) * N_ + scol;
    const size_t bBase = ((size_t)(k0o + srow)) * N_ + scol;

    f4v acc[4][4] = {};

    for (int j0 = 0; j0 < N_; j0 += 32) {
#pragma unroll
        for (int t = 0; t < 2; ++t) {
            size_t so = (size_t)t * 64 * N_ + j0;
            int    dd = t * 2048 + tid * 8;
            gl_lds16(P  + aBase + so, &As[dd]);
            gl_lds16(Wb + bBase + so, &Bs[dd]);
        }
        __syncthreads();

        bf8v a[4], bb[4];
#pragma unroll
        for (int mi = 0; mi < 4; ++mi) a[mi]  = *(const bf8v*)&As[(im + mi * 16 + fr) * 32 + fk];
#pragma unroll
        for (int ni = 0; ni < 4; ++ni) bb[ni] = *(const bf8v*)&Bs[(jn + ni * 16 + fr) * 32 + fk];
#pragma unroll
        for (int mi = 0; mi < 4; ++mi)
#pragma unroll
            for (int ni = 0; ni < 4; ++ni)
                acc[mi][ni] = __builtin_amdgcn_mfma_f32_16x16x32_bf16(a[mi], bb[ni], acc[mi][ni], 0, 0, 0);

        __syncthreads();
    }

#pragma unroll
    for (int mi = 0; mi < 4; ++mi)
#pragma unroll
        for (int r = 0; r < 4; ++r) {
            int i = i0 + im + mi * 16 + q4 + r;
#pragma unroll
            for (int ni = 0; ni < 4; ++ni) {
                int k = k0o + jn + ni * 16 + fr;
                out[((size_t)(b * N_ + i)) * N_ + k] = acc[mi][ni][r];
            }
        }
}

// ===========================================================================
// Fallback fp32 path (round-1 kernels) — used only if ws_size is too small.
// ===========================================================================
__global__ __launch_bounds__(256) void rowsum_kernel(const float* __restrict__ x,
                                                     float* __restrict__ sq,
                                                     float* __restrict__ s) {
    int row  = blockIdx.x * 4 + (threadIdx.x >> 6);
    int lane = threadIdx.x & 63;
    const float4* xr = (const float4*)(x + (size_t)row * F_);
    float a1 = 0.f, a2 = 0.f;
#pragma unroll
    for (int it = 0; it < 4; ++it) {
        float4 v = xr[lane + it * 64];
        a1 += v.x + v.y + v.z + v.w;
        a2 += v.x * v.x + v.y * v.y + v.z * v.z + v.w * v.w;
    }
#pragma unroll
    for (int off = 32; off > 0; off >>= 1) {
        a1 += __shfl_xor(a1, off);
        a2 += __shfl_xor(a2, off);
    }
    if (lane == 0) { s[row] = a1; sq[row] = a2; }
}

__global__ __launch_bounds__(256) void dist_kernel(const float* __restrict__ x,
                                                   const float* __restrict__ sq,
                                                   const float* __restrict__ s,
                                                   float* __restrict__ dist) {
    const int b   = blockIdx.z;
    const int ib0 = blockIdx.y * 64;
    const int jb0 = blockIdx.x * 64;
    __shared__ float As[16][68];
    __shared__ float Bs[16][68];
    const float* Xb = x + (size_t)b * N_ * F_;
    const int tid   = threadIdx.x;
    const int lrow  = tid >> 2;
    const int lcol4 = (tid & 3) * 4;
    const int tx4   = (tid & 15) * 4;
    const int ty4   = (tid >> 4) * 4;
    float acc[4][4] = {};
    for (int k0 = 0; k0 < F_; k0 += 16) {
        float4 av = *(const float4*)(Xb + (size_t)(ib0 + lrow) * F_ + k0 + lcol4);
        float4 bv = *(const float4*)(Xb + (size_t)(jb0 + lrow) * F_ + k0 + lcol4);
        __syncthreads();
        As[lcol4 + 0][lrow] = av.x; As[lcol4 + 1][lrow] = av.y;
        As[lcol4 + 2][lrow] = av.z; As[lcol4 + 3][lrow] = av.w;
        Bs[lcol4 + 0][lrow] = bv.x; Bs[lcol4 + 1][lrow] = bv.y;
        Bs[lcol4 + 2][lrow] = bv.z; Bs[lcol4 + 3][lrow] = bv.w;
        __syncthreads();
#pragma unroll
        for (int k = 0; k < 16; ++k) {
            float ar[4], br[4];
#pragma unroll
            for (int t = 0; t < 4; ++t) { ar[t] = As[k][ty4 + t]; br[t] = Bs[k][tx4 + t]; }
#pragma unroll
            for (int mi = 0; mi < 4; ++mi)
#pragma unroll
                for (int ni = 0; ni < 4; ++ni)
                    acc[mi][ni] = fmaf(ar[mi], br[ni], acc[mi][ni]);
        }
    }
    float sqi[4], si[4], sqj[4], sj[4];
#pragma unroll
    for (int t = 0; t < 4; ++t) {
        sqi[t] = sq[b * N_ + ib0 + ty4 + t];
        si[t]  = s [b * N_ + ib0 + ty4 + t];
        sqj[t] = sq[b * N_ + jb0 + tx4 + t];
        sj[t]  = s [b * N_ + jb0 + tx4 + t];
    }
#pragma unroll
    for (int mi = 0; mi < 4; ++mi) {
        int gi = ib0 + ty4 + mi;
        float4 o; float v[4];
#pragma unroll
        for (int ni = 0; ni < 4; ++ni) {
            int gj = jb0 + tx4 + ni;
            float d2 = sqi[mi] + sqj[ni] - 2.f * acc[mi][ni]
                     + 2.f * EPS * (si[mi] - sj[ni]) + (float)F_ * EPS * EPS;
            float d = sqrtf(fmaxf(d2, 0.f));
            v[ni] = (gi == gj) ? 0.f : d;
        }
        o.x = v[0]; o.y = v[1]; o.z = v[2]; o.w = v[3];
        *(float4*)(dist + ((size_t)(b * N_ + gi)) * N_ + jb0 + tx4) = o;
    }
}

__global__ __launch_bounds__(256) void softmax_p2(const float* __restrict__ pm,
                                                  const float* __restrict__ pl,
                                                  float* __restrict__ m,
                                                  float* __restrict__ rl) {
    int b = blockIdx.y;
    int j = blockIdx.x * 256 + threadIdx.x;
    float mx = -1e30f;
#pragma unroll
    for (int c = 0; c < 8; ++c) mx = fmaxf(mx, pm[((size_t)c * B_ + b) * N_ + j]);
    float l = 0.f;
#pragma unroll
    for (int c = 0; c < 8; ++c)
        l += pl[((size_t)c * B_ + b) * N_ + j] * __expf(pm[((size_t)c * B_ + b) * N_ + j] - mx);
    m[b * N_ + j]  = mx;
    rl[b * N_ + j] = 1.f / l;
}

__global__ __launch_bounds__(256) void out_kernel(const float* __restrict__ dist,
                                                  const float* __restrict__ m,
                                                  const float* __restrict__ rl,
                                                  const float* __restrict__ W,
                                                  float* __restrict__ out) {
    const int b  = blockIdx.z;
    const int i0 = blockIdx.y * 64;
    const int k0 = blockIdx.x * 64;
    __shared__ float Ps[16][68];
    __shared__ float Ws[16][68];
    const int tid   = threadIdx.x;
    const int lrow  = tid >> 2;
    const int lcol4 = (tid & 3) * 4;
    const int tx4   = (tid & 15) * 4;
    const int ty4   = (tid >> 4) * 4;
    float acc[4][4] = {};
    for (int j0 = 0; j0 < N_; j0 += 16) {
        float4 dv  = *(const float4*)(dist + ((size_t)(b * N_ + i0 + lrow)) * N_ + j0 + lcol4);
        float4 mj  = *(const float4*)(m  + b * N_ + j0 + lcol4);
        float4 rj  = *(const float4*)(rl + b * N_ + j0 + lcol4);
        float4 wv  = *(const float4*)(W + (size_t)(k0 + lrow) * N_ + j0 + lcol4);
        __syncthreads();
        Ps[lcol4 + 0][lrow] = __expf(dv.x - mj.x) * rj.x;
        Ps[lcol4 + 1][lrow] = __expf(dv.y - mj.y) * rj.y;
        Ps[lcol4 + 2][lrow] = __expf(dv.z - mj.z) * rj.z;
        Ps[lcol4 + 3][lrow] = __expf(dv.w - mj.w) * rj.w;
        Ws[lcol4 + 0][lrow] = wv.x; Ws[lcol4 + 1][lrow] = wv.y;
        Ws[lcol4 + 2][lrow] = wv.z; Ws[lcol4 + 3][lrow] = wv.w;
        __syncthreads();
#pragma unroll
        for (int k = 0; k < 16; ++k) {
            float pr[4], wr[4];
#pragma unroll
            for (int t = 0; t < 4; ++t) { pr[t] = Ps[k][ty4 + t]; wr[t] = Ws[k][tx4 + t]; }
#pragma unroll
            for (int mi = 0; mi < 4; ++mi)
#pragma unroll
                for (int ni = 0; ni < 4; ++ni)
                    acc[mi][ni] = fmaf(pr[mi], wr[ni], acc[mi][ni]);
        }
    }
#pragma unroll
    for (int mi = 0; mi < 4; ++mi) {
        float4 o;
        o.x = acc[mi][0]; o.y = acc[mi][1]; o.z = acc[mi][2]; o.w = acc[mi][3];
        *(float4*)(out + ((size_t)(b * N_ + i0 + ty4 + mi)) * N_ + k0 + tx4) = o;
    }
}

// ---------------------------------------------------------------------------
extern "C" void kernel_launch(void* const* d_in, const int* in_sizes, int n_in,
                              void* d_out, int out_size, void* d_ws, size_t ws_size,
                              hipStream_t stream) {
    const float* x = (const float*)d_in[0];
    const float* W = (const float*)d_in[1];
    float* out = (float*)d_out;

    const size_t NN  = (size_t)B_ * N_ * N_;   // 8.4M
    const size_t NF2 = (size_t)B_ * N_ * F_ / 2;  // bf16 array in float slots

    // fast-path layout (float slots)
    size_t need = NN + 2 * NF2 + (size_t)N_ * N_ / 2 + 2 * (size_t)B_ * N_ + 2 * (size_t)8 * B_ * N_;

    float* ws = (float*)d_ws;

    if (ws_size >= need * sizeof(float)) {
        float*  dist = ws;
        __bf16* xhi  = (__bf16*)(ws + NN);          // P aliases this after dist GEMM
        __bf16* xlo  = (__bf16*)(ws + NN + NF2);
        __bf16* Wb   = (__bf16*)(ws + NN + 2 * NF2);
        float*  sq   = ws + NN + 2 * NF2 + (size_t)N_ * N_ / 2;
        float*  s    = sq + (size_t)B_ * N_;
        float*  pm   = s  + (size_t)B_ * N_;
        float*  pl   = pm + (size_t)8 * B_ * N_;
        __bf16* P    = xhi;

        rowsumcvt_kernel<<<B_ * N_ / 4, 256, 0, stream>>>(x, sq, s, xhi, xlo);
        wcvt_kernel<<<N_ * N_ / 1024, 256, 0, stream>>>(W, Wb);
        dist_mfma<<<dim3(N_ / 128, N_ / 128, B_), 256, 0, stream>>>(xhi, xlo, sq, s, dist);
        softmax_p1<<<dim3(N_ / 256, 8, B_), 256, 0, stream>>>(dist, pm, pl);
        pcvt_kernel<<<dim3(N_ / 128, B_), 256, 0, stream>>>(dist, pm, pl, P);
        out_mfma<<<dim3(N_ / 128, N_ / 128, B_), 256, 0, stream>>>(P, Wb, out);
    } else {
        float* dist = ws;
        float* sq   = dist + NN;
        float* s    = sq + B_ * N_;
        float* m    = s  + B_ * N_;
        float* rl   = m  + B_ * N_;
        float* pm   = rl + B_ * N_;
        float* pl   = pm + 8 * B_ * N_;

        rowsum_kernel<<<B_ * N_ / 4, 256, 0, stream>>>(x, sq, s);
        dist_kernel<<<dim3(N_ / 64, N_ / 64, B_), 256, 0, stream>>>(x, sq, s, dist);
        softmax_p1<<<dim3(N_ / 256, 8, B_), 256, 0, stream>>>(dist, pm, pl);
        softmax_p2<<<dim3(N_ / 256, B_), 256, 0, stream>>>(pm, pl, m, rl);
        out_kernel<<<dim3(N_ / 64, N_ / 64, B_), 256, 0, stream>>>(dist, m, rl, W, out);
    }
}

// Round 3
// 173.275 us; speedup vs baseline: 2.7611x; 1.3858x over previous
//
#include <hip/hip_runtime.h>
#include <math.h>

#define B_ 32
#define N_ 512
#define F_ 1024
#define EPS 1e-6f

typedef _Float16 h8v __attribute__((ext_vector_type(8)));
typedef _Float16 h4v __attribute__((ext_vector_type(4)));
typedef float    f4v __attribute__((ext_vector_type(4)));

__device__ __forceinline__ void gl_lds16(const void* g, void* l) {
    __builtin_amdgcn_global_load_lds(
        (const __attribute__((address_space(1))) unsigned int*)g,
        (__attribute__((address_space(3))) unsigned int*)l, 16, 0, 0);
}

// ---------------------------------------------------------------------------
// Kernel A: per-row sum/sumsq + x -> fp16. One wave per row.
// ---------------------------------------------------------------------------
__global__ __launch_bounds__(256) void rowsumcvt_kernel(const float* __restrict__ x,
                                                        float* __restrict__ sq,
                                                        float* __restrict__ s,
                                                        _Float16* __restrict__ xh) {
    int row  = blockIdx.x * 4 + (threadIdx.x >> 6);
    int lane = threadIdx.x & 63;
    const float4* xr = (const float4*)(x + (size_t)row * F_);
    float a1 = 0.f, a2 = 0.f;
#pragma unroll
    for (int it = 0; it < 4; ++it) {
        float4 v = xr[lane + it * 64];
        a1 += v.x + v.y + v.z + v.w;
        a2 += v.x * v.x + v.y * v.y + v.z * v.z + v.w * v.w;
        h4v h;
        h[0] = (_Float16)v.x; h[1] = (_Float16)v.y;
        h[2] = (_Float16)v.z; h[3] = (_Float16)v.w;
        *(h4v*)&xh[(size_t)row * F_ + (size_t)(lane + it * 64) * 4] = h;
    }
#pragma unroll
    for (int off = 32; off > 0; off >>= 1) {
        a1 += __shfl_xor(a1, off);
        a2 += __shfl_xor(a2, off);
    }
    if (lane == 0) { s[row] = a1; sq[row] = a2; }
}

// W -> fp16
__global__ __launch_bounds__(256) void wcvt_kernel(const float* __restrict__ W,
                                                   _Float16* __restrict__ Wh) {
    size_t e = ((size_t)blockIdx.x * 256 + threadIdx.x) * 4;
    float4 v = *(const float4*)(W + e);
    h4v h;
    h[0] = (_Float16)v.x; h[1] = (_Float16)v.y;
    h[2] = (_Float16)v.z; h[3] = (_Float16)v.w;
    *(h4v*)&Wh[e] = h;
}

// ---------------------------------------------------------------------------
// Kernel B: dist via fp16 MFMA GEMM (128x128 tile, BK=32) with FUSED partial
// column-softmax stats (per 128-row chunk) in the epilogue.
// pm/pl layout: [ic(4)][B][N].
// ---------------------------------------------------------------------------
__global__ __launch_bounds__(256) void dist_mfma(const _Float16* __restrict__ xh,
                                                 const float* __restrict__ sq,
                                                 const float* __restrict__ s,
                                                 float* __restrict__ dist,
                                                 float* __restrict__ pm,
                                                 float* __restrict__ pl) {
    const int b  = blockIdx.z;
    const int i0 = blockIdx.y * 128;
    const int j0 = blockIdx.x * 128;

    __shared__ __align__(16) _Float16 Ah[128 * 32];
    __shared__ __align__(16) _Float16 Bh[128 * 32];
    __shared__ float sm_m[2][128];
    __shared__ float sm_s[2][128];

    const int tid  = threadIdx.x;
    const int lane = tid & 63;
    const int w    = tid >> 6;
    const int im   = (w >> 1) * 64;
    const int jn   = (w & 1) * 64;
    const int fr   = lane & 15;
    const int fk   = (lane >> 4) * 8;
    const int q4   = (lane >> 4) * 4;

    const int srow = tid >> 2;
    const int scol = (tid & 3) * 8;
    const size_t aBase = ((size_t)(b * N_ + i0 + srow)) * F_ + scol;
    const size_t bBase = ((size_t)(b * N_ + j0 + srow)) * F_ + scol;

    f4v acc[4][4] = {};

    for (int k0 = 0; k0 < F_; k0 += 32) {
#pragma unroll
        for (int t = 0; t < 2; ++t) {
            size_t so = (size_t)t * 64 * F_ + k0;
            int    dd = t * 2048 + tid * 8;
            gl_lds16(xh + aBase + so, &Ah[dd]);
            gl_lds16(xh + bBase + so, &Bh[dd]);
        }
        __syncthreads();

        h8v a[4], bb[4];
#pragma unroll
        for (int mi = 0; mi < 4; ++mi) a[mi]  = *(const h8v*)&Ah[(im + mi * 16 + fr) * 32 + fk];
#pragma unroll
        for (int ni = 0; ni < 4; ++ni) bb[ni] = *(const h8v*)&Bh[(jn + ni * 16 + fr) * 32 + fk];
#pragma unroll
        for (int mi = 0; mi < 4; ++mi)
#pragma unroll
            for (int ni = 0; ni < 4; ++ni)
                acc[mi][ni] = __builtin_amdgcn_mfma_f32_16x16x32_f16(a[mi], bb[ni], acc[mi][ni], 0, 0, 0);

        __syncthreads();
    }

    // --- epilogue 1: transform acc -> dist values, store ---
    float sqj[4], sj[4];
#pragma unroll
    for (int ni = 0; ni < 4; ++ni) {
        int j = j0 + jn + ni * 16 + fr;
        sqj[ni] = sq[b * N_ + j];
        sj[ni]  = s [b * N_ + j];
    }
#pragma unroll
    for (int mi = 0; mi < 4; ++mi)
#pragma unroll
        for (int r = 0; r < 4; ++r) {
            int i = i0 + im + mi * 16 + q4 + r;
            float sqi = sq[b * N_ + i];
            float si  = s [b * N_ + i];
#pragma unroll
            for (int ni = 0; ni < 4; ++ni) {
                int j = j0 + jn + ni * 16 + fr;
                float d2 = sqi + sqj[ni] - 2.f * acc[mi][ni][r]
                         + 2.f * EPS * (si - sj[ni]) + (float)F_ * EPS * EPS;
                float dd = (i == j) ? 0.f : sqrtf(fmaxf(d2, 0.f));
                acc[mi][ni][r] = dd;
                dist[((size_t)(b * N_ + i)) * N_ + j] = dd;
            }
        }

    // --- epilogue 2: per-column (over the tile's 128 rows) max + sum-exp ---
#pragma unroll
    for (int ni = 0; ni < 4; ++ni) {
        float m_l = -1e30f;
#pragma unroll
        for (int mi = 0; mi < 4; ++mi)
#pragma unroll
            for (int r = 0; r < 4; ++r) m_l = fmaxf(m_l, acc[mi][ni][r]);
        float s_l = 0.f;
#pragma unroll
        for (int mi = 0; mi < 4; ++mi)
#pragma unroll
            for (int r = 0; r < 4; ++r) s_l += __expf(acc[mi][ni][r] - m_l);
        // combine across the 4 lanes holding the same column (xor 16, 32)
#pragma unroll
        for (int off = 16; off < 64; off <<= 1) {
            float m_o = __shfl_xor(m_l, off);
            float s_o = __shfl_xor(s_l, off);
            float nm  = fmaxf(m_l, m_o);
            s_l = s_l * __expf(m_l - nm) + s_o * __expf(m_o - nm);
            m_l = nm;
        }
        if (lane < 16) {
            int col = jn + ni * 16 + lane;
            sm_m[w >> 1][col] = m_l;
            sm_s[w >> 1][col] = s_l;
        }
    }
    __syncthreads();
    if (tid < 128) {
        float m0 = sm_m[0][tid], m1 = sm_m[1][tid];
        float s0 = sm_s[0][tid], s1 = sm_s[1][tid];
        float mm = fmaxf(m0, m1);
        float ss = s0 * __expf(m0 - mm) + s1 * __expf(m1 - mm);
        size_t o = ((size_t)blockIdx.y * B_ + b) * N_ + j0 + tid;
        pm[o] = mm;
        pl[o] = ss;
    }
}

// ---------------------------------------------------------------------------
// Kernel C: combine 4 partials -> (m, 1/l) per column; emit P = softmax in fp16.
// Block = (128-row chunk) x batch.
// ---------------------------------------------------------------------------
__global__ __launch_bounds__(256) void pcvt_kernel(const float* __restrict__ dist,
                                                   const float* __restrict__ pm,
                                                   const float* __restrict__ pl,
                                                   _Float16* __restrict__ P) {
    __shared__ float ms[N_], rls[N_];
    const int b = blockIdx.y, ic = blockIdx.x;
    const int tid = threadIdx.x;

    for (int j = tid; j < N_; j += 256) {
        float mx = -1e30f;
#pragma unroll
        for (int c = 0; c < 4; ++c) mx = fmaxf(mx, pm[((size_t)c * B_ + b) * N_ + j]);
        float l = 0.f;
#pragma unroll
        for (int c = 0; c < 4; ++c)
            l += pl[((size_t)c * B_ + b) * N_ + j] * __expf(pm[((size_t)c * B_ + b) * N_ + j] - mx);
        ms[j]  = mx;
        rls[j] = 1.f / l;
    }
    __syncthreads();

    const size_t base = ((size_t)(b * N_) + ic * 128) * N_;
    for (int it = 0; it < 64; ++it) {
        int flat = it * 1024 + tid * 4;
        float4 d = *(const float4*)(dist + base + flat);
        int col = flat & (N_ - 1);
        h4v p;
        p[0] = (_Float16)(__expf(d.x - ms[col + 0]) * rls[col + 0]);
        p[1] = (_Float16)(__expf(d.y - ms[col + 1]) * rls[col + 1]);
        p[2] = (_Float16)(__expf(d.z - ms[col + 2]) * rls[col + 2]);
        p[3] = (_Float16)(__expf(d.w - ms[col + 3]) * rls[col + 3]);
        *(h4v*)&P[base + flat] = p;
    }
}

// ---------------------------------------------------------------------------
// Kernel D: out = P @ W^T via fp16 MFMA. 128x128 / BK=32.
// ---------------------------------------------------------------------------
__global__ __launch_bounds__(256) void out_mfma(const _Float16* __restrict__ P,
                                                const _Float16* __restrict__ Wh,
                                                float* __restrict__ out) {
    const int b   = blockIdx.z;
    const int i0  = blockIdx.y * 128;
    const int k0o = blockIdx.x * 128;

    __shared__ __align__(16) _Float16 As[128 * 32];
    __shared__ __align__(16) _Float16 Bs[128 * 32];

    const int tid  = threadIdx.x;
    const int lane = tid & 63;
    const int w    = tid >> 6;
    const int im   = (w >> 1) * 64;
    const int jn   = (w & 1) * 64;
    const int fr   = lane & 15;
    const int fk   = (lane >> 4) * 8;
    const int q4   = (lane >> 4) * 4;

    const int srow = tid >> 2;
    const int scol = (tid & 3) * 8;
    const size_t aBase = ((size_t)(b * N_ + i0 + srow)) * N_ + scol;
    const size_t bBase = ((size_t)(k0o + srow)) * N_ + scol;

    f4v acc[4][4] = {};

    for (int j0 = 0; j0 < N_; j0 += 32) {
#pragma unroll
        for (int t = 0; t < 2; ++t) {
            size_t so = (size_t)t * 64 * N_ + j0;
            int    dd = t * 2048 + tid * 8;
            gl_lds16(P  + aBase + so, &As[dd]);
            gl_lds16(Wh + bBase + so, &Bs[dd]);
        }
        __syncthreads();

        h8v a[4], bb[4];
#pragma unroll
        for (int mi = 0; mi < 4; ++mi) a[mi]  = *(const h8v*)&As[(im + mi * 16 + fr) * 32 + fk];
#pragma unroll
        for (int ni = 0; ni < 4; ++ni) bb[ni] = *(const h8v*)&Bs[(jn + ni * 16 + fr) * 32 + fk];
#pragma unroll
        for (int mi = 0; mi < 4; ++mi)
#pragma unroll
            for (int ni = 0; ni < 4; ++ni)
                acc[mi][ni] = __builtin_amdgcn_mfma_f32_16x16x32_f16(a[mi], bb[ni], acc[mi][ni], 0, 0, 0);

        __syncthreads();
    }

#pragma unroll
    for (int mi = 0; mi < 4; ++mi)
#pragma unroll
        for (int r = 0; r < 4; ++r) {
            int i = i0 + im + mi * 16 + q4 + r;
#pragma unroll
            for (int ni = 0; ni < 4; ++ni) {
                int k = k0o + jn + ni * 16 + fr;
                out[((size_t)(b * N_ + i)) * N_ + k] = acc[mi][ni][r];
            }
        }
}

// ---------------------------------------------------------------------------
extern "C" void kernel_launch(void* const* d_in, const int* in_sizes, int n_in,
                              void* d_out, int out_size, void* d_ws, size_t ws_size,
                              hipStream_t stream) {
    const float* x = (const float*)d_in[0];
    const float* W = (const float*)d_in[1];
    float* out = (float*)d_out;

    const size_t NN  = (size_t)B_ * N_ * N_;       // 8.39M floats
    const size_t NFh = (size_t)B_ * N_ * F_ / 2;   // fp16 x array in float slots

    float*    ws   = (float*)d_ws;
    float*    dist = ws;                            // NN floats
    _Float16* xh   = (_Float16*)(ws + NN);          // B*N*F fp16 (P aliases after dist GEMM)
    _Float16* Wh   = (_Float16*)(ws + NN + NFh);    // N*N fp16
    float*    sq   = ws + NN + NFh + (size_t)N_ * N_ / 2;
    float*    s    = sq + (size_t)B_ * N_;
    float*    pm   = s  + (size_t)B_ * N_;          // 4*B*N
    float*    pl   = pm + (size_t)4 * B_ * N_;      // 4*B*N
    _Float16* P    = xh;

    rowsumcvt_kernel<<<B_ * N_ / 4, 256, 0, stream>>>(x, sq, s, xh);
    wcvt_kernel<<<N_ * N_ / 1024, 256, 0, stream>>>(W, Wh);
    dist_mfma<<<dim3(N_ / 128, N_ / 128, B_), 256, 0, stream>>>(xh, sq, s, dist, pm, pl);
    pcvt_kernel<<<dim3(N_ / 128, B_), 256, 0, stream>>>(dist, pm, pl, P);
    out_mfma<<<dim3(N_ / 128, N_ / 128, B_), 256, 0, stream>>>(P, Wh, out);
}